// Round 14
// baseline (143.468 us; speedup 1.0000x reference)
//
#include <hip/hip_runtime.h>

// Bulk-staged-X kernel: X pair streamed coalesced (dwordx4) -> bf16 LDS tile,
// bx built from LDS columns; weights LDS-resident (R9 layout); single X buffer
// with provably race-free barrier placement.
// out[n,k,c] = sigmoid(s[n,256+c]) * sum_pq F[pq,k]*(T@X1)[pq,c]*(T@X2)[pq,c]
//              + (k==0 ? silu(s[n,c])*s[n,128+c] : 0)

#define KC    49
#define PQ    324
#define NPX   12544     // 49*256
#define OUTK  6272      // 49*128
#define NTILE 11
// LDS weights (bf16):
// T[325][68]: row=pq (324 = zero row), col=i (49..67 zero). 136 B rows.
// F[50][356]: row=k  (49  = zero row), col=pq (324..355 zero). 712 B rows.
#define TROWS 325
#define TCOLS 68
#define FROWS 50
#define FCOLS 356
#define TTOT  (TROWS * TCOLS)        // 22100
#define FTOT  (FROWS * FCOLS)        // 17800
#define WTOT  (TTOT + FTOT)          // 39900 elems
#define WPAD  39904                  // x8 multiple; 79808 B
// LDS X tile: per n [64 i][256 c] bf16 (rows 49..63 zeroed)
#define XBN   16384                  // 64*256 elems per n
#define LDSE  (WPAD + 2 * XBN)       // 72672 elems = 145344 B

typedef __attribute__((ext_vector_type(8)))  short bf16x8;
typedef __attribute__((ext_vector_type(4)))  short bf16x4;
typedef __attribute__((ext_vector_type(16))) float f32x16;
typedef __attribute__((ext_vector_type(4)))  unsigned int u32x4;
typedef __attribute__((ext_vector_type(2)))  unsigned int u32x2;

__device__ __forceinline__ unsigned int cvtpk_bf16(float lo, float hi) {
    unsigned int r;
    asm("v_cvt_pk_bf16_f32 %0, %1, %2" : "=v"(r) : "v"(lo), "v"(hi));
    return r;
}
__device__ __forceinline__ unsigned short f2bf(float f) {
    unsigned u = __builtin_bit_cast(unsigned, f);
    return (unsigned short)((u + 0x7FFFu + ((u >> 16) & 1u)) >> 16);   // RNE
}
// two ds_read_b64 (weight rows are 8-B aligned)
__device__ __forceinline__ bf16x8 ld8(const unsigned short* p) {
    const bf16x4 lo = *(const bf16x4*)p;
    const bf16x4 hi = *(const bf16x4*)(p + 4);
    bf16x8 r;
    r[0] = lo[0]; r[1] = lo[1]; r[2] = lo[2]; r[3] = lo[3];
    r[4] = hi[0]; r[5] = hi[1]; r[6] = hi[2]; r[7] = hi[3];
    return r;
}

__global__ void prep_kernel(const float* __restrict__ Tg, const float* __restrict__ Fg,
                            unsigned short* __restrict__ W)
{
    const int idx = blockIdx.x * 256 + threadIdx.x;
    if (idx < TTOT) {
        const int r = idx / TCOLS, i = idx % TCOLS;
        const float v = (r < PQ && i < KC) ? Tg[r * KC + i] : 0.0f;
        W[idx] = f2bf(v);
    } else if (idx < WPAD) {
        float v = 0.0f;
        if (idx < WTOT) {
            const int idx2 = idx - TTOT;
            const int k = idx2 / FCOLS, p = idx2 % FCOLS;
            if (k < KC && p < PQ) v = Fg[p * KC + k];
        }
        W[idx] = f2bf(v);
    }
}

__global__ __launch_bounds__(512, 2)
void s2_fused(const float* __restrict__ X,            // [N][49][256]
              const float* __restrict__ S,            // [N][384]
              const unsigned short* __restrict__ W,   // T/F blob
              float* __restrict__ out,                // [N][49][128]
              int nit,                                // batches (2 n each)
              float fzero)                            // 0.0f (opaque)
{
    __shared__ __align__(16) unsigned short lds[LDSE];   // 145344 B -> 1 block/CU

    const int tid = threadIdx.x;
    // ---- one-time stage of T/F into LDS ----
    for (int idx = tid; idx < WPAD / 8; idx += 512) {
        const u32x4 v = *(const u32x4*)(W + (size_t)idx * 8);
        *(u32x4*)(lds + (size_t)idx * 8) = v;
    }
    // (covered by the first batch's bar1)

    const int w  = tid >> 6;
    const int l  = tid & 63;
    const int cl = l & 31;
    const int hb = l >> 5;
    const int cs = w >> 1;   // c-slice 0..3 (c = 32*cs + cl)
    const int nw = w & 1;    // which n of the staged pair

    const unsigned short* tw  = lds;
    const unsigned short* fw0 = lds + TTOT + (size_t)cl * FCOLS;                 // k = cl
    const unsigned short* fw1 = lds + TTOT + (size_t)min(cl + 32, KC) * FCOLS;   // k = 32+cl
    unsigned short* XB = lds + WPAD;

    // opaque zero accumulator (16 regs, reused as MFMA C-in)
    f32x16 Z;
#pragma unroll
    for (int r = 0; r < 16; ++r) Z[r] = fzero;

    for (int it = 0; it < nit; ++it) {
        const int base = blockIdx.x * (2 * nit) + 2 * it;   // first n of pair

        // ---- cooperative bulk stage: X[base..base+1] -> bf16 LDS tiles ----
        // 8192 quads (2n x 64i x 256c /4), 16 exact rounds; i>=49 zero-filled.
        for (int q = tid; q < 8192; q += 512) {
            const int nq  = q >> 12;          // 4096 quads per n
            const int rem = q & 4095;
            const int i   = rem >> 6;
            const int c4  = (rem & 63) << 2;
            float4 v = make_float4(0.f, 0.f, 0.f, 0.f);
            if (i < KC)
                v = *(const float4*)(X + (size_t)(base + nq) * NPX + i * 256 + c4);
            u32x2 d;
            d[0] = cvtpk_bf16(v.x, v.y);
            d[1] = cvtpk_bf16(v.z, v.w);
            *(u32x2*)(XB + nq * XBN + i * 256 + c4) = d;
        }
        __syncthreads();   // bar1: XB (and, on it==0, weights) ready

        // ---- scalars ----
        const int n = base + nw;
        const float* sp = S + (size_t)n * 384 + 32 * cs + cl;
        const float sraw0 = sp[0], sraw1 = sp[128], sraw2 = sp[256];
        const float sg  = 1.0f / (1.0f + __expf(-sraw2));
        const float osc = (sraw0 / (1.0f + __expf(-sraw0))) * sraw1;

        // ---- bx from LDS columns (2-way-banked u16 reads, short latency) ----
        bf16x8 bx[2][4];
        {
            const unsigned short* xb = XB + nw * XBN + 32 * cs + cl;
#pragma unroll
            for (int xi = 0; xi < 2; ++xi)
#pragma unroll
            for (int st = 0; st < 4; ++st) {
                bf16x8 t;
#pragma unroll
                for (int j = 0; j < 8; ++j)
                    t[j] = (short)xb[(16 * st + 8 * hb + j) * 256 + 128 * xi];
                bx[xi][st] = t;
            }
        }
        __syncthreads();   // bar2: all waves done reading XB -> next stage may overwrite

        f32x16 accO0, accO1;
#pragma unroll
        for (int r = 0; r < 16; ++r) { accO0[r] = 0.0f; accO1[r] = 0.0f; }

        for (int t = 0; t < NTILE; ++t) {
            const int trow = min(32 * t + cl, 324);
            const unsigned short* twt = tw + trow * TCOLS + 8 * hb;

            // GEMM1: K=64 in 4 steps; C-init from opaque Z
            f32x16 ac0, ac1;
            {
                const bf16x8 ta0 = ld8(twt);
                const bf16x8 ta1 = ld8(twt + 16);
                ac0 = __builtin_amdgcn_mfma_f32_32x32x16_bf16(ta0, bx[0][0], Z, 0, 0, 0);
                ac1 = __builtin_amdgcn_mfma_f32_32x32x16_bf16(ta0, bx[1][0], Z, 0, 0, 0);
                ac0 = __builtin_amdgcn_mfma_f32_32x32x16_bf16(ta1, bx[0][1], ac0, 0, 0, 0);
                ac1 = __builtin_amdgcn_mfma_f32_32x32x16_bf16(ta1, bx[1][1], ac1, 0, 0, 0);
            }
            {
                const bf16x8 ta2 = ld8(twt + 32);
                const bf16x8 ta3 = ld8(twt + 48);
                ac0 = __builtin_amdgcn_mfma_f32_32x32x16_bf16(ta2, bx[0][2], ac0, 0, 0, 0);
                ac1 = __builtin_amdgcn_mfma_f32_32x32x16_bf16(ta2, bx[1][2], ac1, 0, 0, 0);
                ac0 = __builtin_amdgcn_mfma_f32_32x32x16_bf16(ta3, bx[0][3], ac0, 0, 0, 0);
                ac1 = __builtin_amdgcn_mfma_f32_32x32x16_bf16(ta3, bx[1][3], ac1, 0, 0, 0);
            }

            // issue F-frags early (hide under pack VALU)
            const int fcol = 32 * t + 8 * hb;
            const bf16x8 fa00 = ld8(fw0 + fcol);
            const bf16x8 fa01 = ld8(fw0 + fcol + 16);
            const bf16x8 fa10 = ld8(fw1 + fcol);
            const bf16x8 fa11 = ld8(fw1 + fcol + 16);

            // gate + pack to bf16 pairs
            unsigned int q0 = cvtpk_bf16(ac0[0]  * ac1[0],  ac0[1]  * ac1[1]);
            unsigned int q1 = cvtpk_bf16(ac0[2]  * ac1[2],  ac0[3]  * ac1[3]);
            unsigned int q2 = cvtpk_bf16(ac0[4]  * ac1[4],  ac0[5]  * ac1[5]);
            unsigned int q3 = cvtpk_bf16(ac0[6]  * ac1[6],  ac0[7]  * ac1[7]);
            unsigned int q4 = cvtpk_bf16(ac0[8]  * ac1[8],  ac0[9]  * ac1[9]);
            unsigned int q5 = cvtpk_bf16(ac0[10] * ac1[10], ac0[11] * ac1[11]);
            unsigned int q6 = cvtpk_bf16(ac0[12] * ac1[12], ac0[13] * ac1[13]);
            unsigned int q7 = cvtpk_bf16(ac0[14] * ac1[14], ac0[15] * ac1[15]);

            // half-wave exchange: C-layout (4-row groups) -> B-frag (8-row groups)
            asm("v_permlane32_swap_b32 %0, %1" : "+v"(q0), "+v"(q2));
            asm("v_permlane32_swap_b32 %0, %1" : "+v"(q1), "+v"(q3));
            asm("v_permlane32_swap_b32 %0, %1" : "+v"(q4), "+v"(q6));
            asm("v_permlane32_swap_b32 %0, %1" : "+v"(q5), "+v"(q7));
            u32x4 b0v, b1v;
            b0v[0] = q0; b0v[1] = q1; b0v[2] = q2; b0v[3] = q3;
            b1v[0] = q4; b1v[1] = q5; b1v[2] = q6; b1v[3] = q7;
            const bf16x8 bg0 = __builtin_bit_cast(bf16x8, b0v);
            const bf16x8 bg1 = __builtin_bit_cast(bf16x8, b1v);

            // GEMM2: out-tiles k 0..31 / 32..48
            accO0 = __builtin_amdgcn_mfma_f32_32x32x16_bf16(fa00, bg0, accO0, 0, 0, 0);
            accO1 = __builtin_amdgcn_mfma_f32_32x32x16_bf16(fa10, bg0, accO1, 0, 0, 0);
            accO0 = __builtin_amdgcn_mfma_f32_32x32x16_bf16(fa01, bg1, accO0, 0, 0, 0);
            accO1 = __builtin_amdgcn_mfma_f32_32x32x16_bf16(fa11, bg1, accO1, 0, 0, 0);
        }

        // ---- epilogue: gate, SwiGLU merge at k==0, store ----
        float* op = out + (size_t)n * OUTK + 32 * cs + cl;
#pragma unroll
        for (int r = 0; r < 16; ++r) {
            const int k0 = (r & 3) + 8 * (r >> 2) + 4 * hb;
            float v = sg * accO0[r];
            if (k0 == 0) v += osc;               // only r==0, hb==0
            op[(size_t)k0 * 128] = v;
            const int k1 = 32 + k0;
            if (k1 < KC) op[(size_t)k1 * 128] = sg * accO1[r];
        }
    }
}

extern "C" void kernel_launch(void* const* d_in, const int* in_sizes, int n_in,
                              void* d_out, int out_size, void* d_ws, size_t ws_size,
                              hipStream_t stream) {
    const float* inputs  = (const float*)d_in[0];
    const float* scalars = (const float*)d_in[1];
    const float* Tg      = (const float*)d_in[2];
    const float* Fg      = (const float*)d_in[3];
    float* outp          = (float*)d_out;

    unsigned short* W = (unsigned short*)d_ws;   // WPAD elems = 79808 B

    const int N = in_sizes[1] / 384;             // 4096
    hipLaunchKernelGGL(prep_kernel, dim3((WPAD + 255) / 256), dim3(256), 0, stream,
                       Tg, Fg, W);

    const int nit  = 4;                          // batches of 2 n
    const int grid = N / (2 * nit);              // 512 blocks
    hipLaunchKernelGGL(s2_fused, dim3(grid), dim3(512), 0, stream,
                       inputs, scalars, W, outp, nit, 0.0f);
}

// Round 15
// 95.538 us; speedup vs baseline: 1.5017x; 1.5017x over previous
//
#include <hip/hip_runtime.h>

// Fragment-major-LDS kernel: weight frags stored so each lane's 16B sits at
// base + lane*16 -> single conflict-free ds_read_b128 per frag, zero in-loop
// LDS address math (full tile unroll, immediate offsets).
// out[n,k,c] = sigmoid(s[n,256+c]) * sum_pq F[pq,k]*(T@X1)[pq,c]*(T@X2)[pq,c]
//              + (k==0 ? silu(s[n,c])*s[n,128+c] : 0)

#define KC    49
#define PQ    324
#define NPX   12544     // 49*256
#define OUTK  6272      // 49*128
#define NTILE 11
// Fragment-major weight blobs (bf16), built by prep_kernel:
// TF[t][f][lane 64][8] : T_pad[pq=32t+(l&31)][i=16f+8*(l>>5)+j]
// FF[t][g][h][lane 64][8] : F^T_pad[k=32g+(l&31)][pq=32t+16h+8*(l>>5)+j]
#define TFTOT 22528     // 11*4*64*8 elems (45056 B)
#define FFTOT 22528     // 11*2*2*64*8 elems
#define WTOT  (TFTOT + FFTOT)   // 45056 elems = 90112 B

typedef __attribute__((ext_vector_type(8)))  short bf16x8;
typedef __attribute__((ext_vector_type(16))) float f32x16;
typedef __attribute__((ext_vector_type(4)))  unsigned int u32x4;

__device__ __forceinline__ unsigned int cvtpk_bf16(float lo, float hi) {
    unsigned int r;
    asm("v_cvt_pk_bf16_f32 %0, %1, %2" : "=v"(r) : "v"(lo), "v"(hi));
    return r;
}
__device__ __forceinline__ unsigned short f2bf(float f) {
    unsigned u = __builtin_bit_cast(unsigned, f);
    return (unsigned short)((u + 0x7FFFu + ((u >> 16) & 1u)) >> 16);   // RNE
}
// 8-dword strided X chunk load (i-rows 16*st+8*hb .. +7, one column)
__device__ __forceinline__ void load_ch(const float* xp, int xi, int st, int hb, float* buf) {
#pragma unroll
    for (int j = 0; j < 8; ++j) {
        const int i = 16 * st + 8 * hb + j;
        buf[j] = (i < KC) ? xp[128 * xi + (size_t)i * 256] : 0.0f;
    }
}
__device__ __forceinline__ bf16x8 cvt_ch(const float* buf) {
    u32x4 d;
#pragma unroll
    for (int p = 0; p < 4; ++p) d[p] = cvtpk_bf16(buf[2 * p], buf[2 * p + 1]);
    return __builtin_bit_cast(bf16x8, d);
}

__global__ void prep_kernel(const float* __restrict__ Tg, const float* __restrict__ Fg,
                            unsigned short* __restrict__ W)
{
    const int idx = blockIdx.x * 256 + threadIdx.x;
    if (idx < TFTOT) {
        const int j = idx & 7;
        const int l = (idx >> 3) & 63;
        const int f = (idx >> 9) & 3;
        const int t = idx >> 11;
        const int pq = 32 * t + (l & 31);
        const int i  = 16 * f + 8 * (l >> 5) + j;
        W[idx] = f2bf((pq < PQ && i < KC) ? Tg[pq * KC + i] : 0.0f);
    } else if (idx < WTOT) {
        const int idx2 = idx - TFTOT;
        const int j = idx2 & 7;
        const int l = (idx2 >> 3) & 63;
        const int h = (idx2 >> 9) & 1;
        const int g = (idx2 >> 10) & 1;
        const int t = idx2 >> 11;
        const int pq = 32 * t + 16 * h + 8 * (l >> 5) + j;
        const int k  = 32 * g + (l & 31);
        W[idx] = f2bf((pq < PQ && k < KC) ? Fg[pq * KC + k] : 0.0f);
    }
}

__global__ __launch_bounds__(512, 2)
void s2_fused(const float* __restrict__ X,            // [N][49][256]
              const float* __restrict__ S,            // [N][384]
              const unsigned short* __restrict__ W,   // TF+FF blob
              float* __restrict__ out,                // [N][49][128]
              int nit,                                // n-pairs per block
              float fzero)                            // 0.0f (opaque)
{
    __shared__ __align__(16) unsigned short lds[WTOT];   // 90112 B

    const int tid = threadIdx.x;
    // ---- one-time stage of TF/FF into LDS (5632 quads, 11 exact rounds) ----
    for (int idx = tid; idx < WTOT / 8; idx += 512) {
        const u32x4 v = *(const u32x4*)(W + (size_t)idx * 8);
        *(u32x4*)(lds + (size_t)idx * 8) = v;
    }
    __syncthreads();   // only barrier; LDS read-only afterwards

    const int w  = tid >> 6;
    const int l  = tid & 63;
    const int cl = l & 31;
    const int hb = l >> 5;
    const int cs = w >> 1;   // c-slice 0..3 (c = 32*cs + cl)
    const int nw = w & 1;    // which n of the pair

    // lane-linear fragment base: frag (t,f) at tf + (t*4+f)*512, all imm-foldable
    const unsigned short* tf = lds + (size_t)(l << 3);
    const unsigned short* ff = tf + TFTOT;

    // opaque zero accumulator (16 regs, reused as MFMA C-in)
    f32x16 Z;
#pragma unroll
    for (int r = 0; r < 16; ++r) Z[r] = fzero;

    const int nbase = blockIdx.x * (2 * nit) + nw;

    for (int it = 0; it < nit; ++it) {
        const int n = nbase + 2 * it;

        const float* xp = X + (size_t)n * NPX + 32 * cs + cl;
        const float* sp = S + (size_t)n * 384 + 32 * cs + cl;
        const float sraw0 = sp[0], sraw1 = sp[128], sraw2 = sp[256];
        const float sg  = 1.0f / (1.0f + __expf(-sraw2));
        const float osc = (sraw0 / (1.0f + __expf(-sraw0))) * sraw1;

        // ---- X gather: 8 chunks x 8 dwords, 4-deep pipeline ----
        bf16x8 bx[2][4];
        {
            float r0[8], r1[8], r2[8], r3[8];
            load_ch(xp, 0, 0, hb, r0);
            load_ch(xp, 1, 0, hb, r1);
            load_ch(xp, 0, 1, hb, r2);
            load_ch(xp, 1, 1, hb, r3);
            bx[0][0] = cvt_ch(r0); load_ch(xp, 0, 2, hb, r0);
            bx[1][0] = cvt_ch(r1); load_ch(xp, 1, 2, hb, r1);
            bx[0][1] = cvt_ch(r2); load_ch(xp, 0, 3, hb, r2);
            bx[1][1] = cvt_ch(r3); load_ch(xp, 1, 3, hb, r3);
            bx[0][2] = cvt_ch(r0);
            bx[1][2] = cvt_ch(r1);
            bx[0][3] = cvt_ch(r2);
            bx[1][3] = cvt_ch(r3);
        }

        f32x16 accO0, accO1;
#pragma unroll
        for (int r = 0; r < 16; ++r) { accO0[r] = 0.0f; accO1[r] = 0.0f; }

#pragma unroll
        for (int t = 0; t < NTILE; ++t) {
            // conflict-free lane-linear b128 frag loads, compile-time offsets
            const bf16x8 ta0 = *(const bf16x8*)(tf + (t * 4 + 0) * 512);
            const bf16x8 ta1 = *(const bf16x8*)(tf + (t * 4 + 1) * 512);
            const bf16x8 ta2 = *(const bf16x8*)(tf + (t * 4 + 2) * 512);
            const bf16x8 ta3 = *(const bf16x8*)(tf + (t * 4 + 3) * 512);

            // GEMM1: K=64 in 4 steps; C-init from opaque Z
            f32x16 ac0, ac1;
            ac0 = __builtin_amdgcn_mfma_f32_32x32x16_bf16(ta0, bx[0][0], Z, 0, 0, 0);
            ac1 = __builtin_amdgcn_mfma_f32_32x32x16_bf16(ta0, bx[1][0], Z, 0, 0, 0);
            ac0 = __builtin_amdgcn_mfma_f32_32x32x16_bf16(ta1, bx[0][1], ac0, 0, 0, 0);
            ac1 = __builtin_amdgcn_mfma_f32_32x32x16_bf16(ta1, bx[1][1], ac1, 0, 0, 0);
            ac0 = __builtin_amdgcn_mfma_f32_32x32x16_bf16(ta2, bx[0][2], ac0, 0, 0, 0);
            ac1 = __builtin_amdgcn_mfma_f32_32x32x16_bf16(ta2, bx[1][2], ac1, 0, 0, 0);
            ac0 = __builtin_amdgcn_mfma_f32_32x32x16_bf16(ta3, bx[0][3], ac0, 0, 0, 0);
            ac1 = __builtin_amdgcn_mfma_f32_32x32x16_bf16(ta3, bx[1][3], ac1, 0, 0, 0);

            // F-frags (issued here; latency hides under the pack VALU)
            const bf16x8 fa00 = *(const bf16x8*)(ff + (t * 4 + 0) * 512);
            const bf16x8 fa01 = *(const bf16x8*)(ff + (t * 4 + 1) * 512);
            const bf16x8 fa10 = *(const bf16x8*)(ff + (t * 4 + 2) * 512);
            const bf16x8 fa11 = *(const bf16x8*)(ff + (t * 4 + 3) * 512);

            // gate + pack to bf16 pairs
            unsigned int q0 = cvtpk_bf16(ac0[0]  * ac1[0],  ac0[1]  * ac1[1]);
            unsigned int q1 = cvtpk_bf16(ac0[2]  * ac1[2],  ac0[3]  * ac1[3]);
            unsigned int q2 = cvtpk_bf16(ac0[4]  * ac1[4],  ac0[5]  * ac1[5]);
            unsigned int q3 = cvtpk_bf16(ac0[6]  * ac1[6],  ac0[7]  * ac1[7]);
            unsigned int q4 = cvtpk_bf16(ac0[8]  * ac1[8],  ac0[9]  * ac1[9]);
            unsigned int q5 = cvtpk_bf16(ac0[10] * ac1[10], ac0[11] * ac1[11]);
            unsigned int q6 = cvtpk_bf16(ac0[12] * ac1[12], ac0[13] * ac1[13]);
            unsigned int q7 = cvtpk_bf16(ac0[14] * ac1[14], ac0[15] * ac1[15]);

            // half-wave exchange: C-layout (4-row groups) -> B-frag (8-row groups)
            asm("v_permlane32_swap_b32 %0, %1" : "+v"(q0), "+v"(q2));
            asm("v_permlane32_swap_b32 %0, %1" : "+v"(q1), "+v"(q3));
            asm("v_permlane32_swap_b32 %0, %1" : "+v"(q4), "+v"(q6));
            asm("v_permlane32_swap_b32 %0, %1" : "+v"(q5), "+v"(q7));
            u32x4 b0v, b1v;
            b0v[0] = q0; b0v[1] = q1; b0v[2] = q2; b0v[3] = q3;
            b1v[0] = q4; b1v[1] = q5; b1v[2] = q6; b1v[3] = q7;
            const bf16x8 bg0 = __builtin_bit_cast(bf16x8, b0v);
            const bf16x8 bg1 = __builtin_bit_cast(bf16x8, b1v);

            // GEMM2: out-tiles k 0..31 / 32..48
            accO0 = __builtin_amdgcn_mfma_f32_32x32x16_bf16(fa00, bg0, accO0, 0, 0, 0);
            accO1 = __builtin_amdgcn_mfma_f32_32x32x16_bf16(fa10, bg0, accO1, 0, 0, 0);
            accO0 = __builtin_amdgcn_mfma_f32_32x32x16_bf16(fa01, bg1, accO0, 0, 0, 0);
            accO1 = __builtin_amdgcn_mfma_f32_32x32x16_bf16(fa11, bg1, accO1, 0, 0, 0);
        }

        // ---- epilogue: gate, SwiGLU merge at k==0, store ----
        float* op = out + (size_t)n * OUTK + 32 * cs + cl;
#pragma unroll
        for (int r = 0; r < 16; ++r) {
            const int k0 = (r & 3) + 8 * (r >> 2) + 4 * hb;
            float v = sg * accO0[r];
            if (k0 == 0) v += osc;               // only r==0, hb==0
            op[(size_t)k0 * 128] = v;
            const int k1 = 32 + k0;
            if (k1 < KC) op[(size_t)k1 * 128] = sg * accO1[r];
        }
    }
}

extern "C" void kernel_launch(void* const* d_in, const int* in_sizes, int n_in,
                              void* d_out, int out_size, void* d_ws, size_t ws_size,
                              hipStream_t stream) {
    const float* inputs  = (const float*)d_in[0];
    const float* scalars = (const float*)d_in[1];
    const float* Tg      = (const float*)d_in[2];
    const float* Fg      = (const float*)d_in[3];
    float* outp          = (float*)d_out;

    unsigned short* W = (unsigned short*)d_ws;   // WTOT elems = 90112 B

    const int N = in_sizes[1] / 384;             // 4096
    hipLaunchKernelGGL(prep_kernel, dim3((WTOT + 255) / 256), dim3(256), 0, stream,
                       Tg, Fg, W);

    const int nit  = 4;                          // n-pairs per block
    const int grid = N / (2 * nit);              // 512 blocks
    hipLaunchKernelGGL(s2_fused, dim3(grid), dim3(512), 0, stream,
                       inputs, scalars, W, outp, nit, 0.0f);
}